// Round 16
// baseline (88.180 us; speedup 1.0000x reference)
//
#include <hip/hip_runtime.h>
#include <math.h>

#define NW 192
#define Wt 193
#define CHUNK 48           // k2 per block
#define NMAIN 768          // 192 k1 x 4 chunks; 512 thr

// cos(2*pi*num*rcpden) via HW cos (input in revolutions)
__device__ __forceinline__ float cos_revr(float num, float rcpden) {
    float rev = num * rcpden;
    rev = __builtin_amdgcn_fractf(rev);
    return __builtin_amdgcn_cosf(rev);
}

// ---------------- k_fused v16: v11 math, 6 barriers instead of 14 ----------------
// Block b: k1 = b>>2, chunk c = b&3 (k2 in [48c,48c+48)). 512 thr = 8 waves.
// LDS carve (manual aliasing, 15552 floats = 62.2 KB -> 2 blocks/CU):
//   xls  = smem[0    .. 3264)   x[p][j] stride 68           (live all of D)
//   win  = smem[3264 .. 6528)   win[p][c] stride 68         (dead after B)
//   part = smem[3264 .. 15552)  [w 8][k2slot 24][i 64]      (aliases win)
// A: win[p][c] coalesced (lane = c).                                [v11]
// B: flip (lane = j, 64/64 lanes): wave w owns p in [6w,6w+6);
//    M row j per-lane global (L1-hot); win uniform LDS b128.        [v15]
// Seeds: d_k = (cos(k1 th)*P[i][j]) * cos(k th) folded into seeds.  [v11]
// D: 2 subs x 24 steps (was 6 x 8): per-block barriers 14 -> 6,
//    reduce phases 6 -> 2. Same 48-step recurrence numerics.        [new]
__global__ __launch_bounds__(512, 4) void k_fused(const float* __restrict__ grid,
                                                  const float* __restrict__ Mw,
                                                  const float* __restrict__ P,
                                                  float* __restrict__ out) {
    __shared__ float smem[15552];
    float* xls  = smem;                 // [p][j], stride 68
    float* win  = smem + 3264;          // [p][c], stride 68 (dead after B)
    float* part = smem + 3264;          // [w][24][64], aliases win

    int bx = blockIdx.x;
    int k1  = bx >> 2;                  // 0..191
    int k2s = (bx & 3) * CHUNK;         // 0,48,96,144
    int t = threadIdx.x;
    int lane = t & 63;
    int w = __builtin_amdgcn_readfirstlane(t >> 6);   // 0..7
    int jb = w * 8;                     // phase-D j range
    int pb6 = w * 6;                    // phase-B p range

    // ---- Phase A: window averages, coalesced (lane = channel c) ----
    {
        int c = lane;
        const float* gb  = grid + ((size_t)k1 * Wt + k2s) * 64 + c;
        const float* gb1 = gb + (size_t)Wt * 64;
        #pragma unroll
        for (int r = 0; r < 6; ++r) {
            int p = pb6 + r;            // 8 waves x 6 = 48 positions
            float s = gb[p * 64] + gb[(p + 1) * 64]
                    + gb1[p * 64] + gb1[(p + 1) * 64];
            win[p * 68 + c] = 0.25f * s;
        }
    }
    __syncthreads();                    // sync1: win visible

    // ---- Phase B (flip): lane = j; x[p][lane] for p in [pb6, pb6+6) ----
    {
        float acc[6];
        #pragma unroll
        for (int pi = 0; pi < 6; ++pi) acc[pi] = 0.f;
        const float4* Mr = (const float4*)(Mw + (size_t)lane * 64);  // own row
        #pragma unroll
        for (int q4 = 0; q4 < 4; ++q4) {
            float4 m0 = Mr[q4 * 4 + 0];
            float4 m1 = Mr[q4 * 4 + 1];
            float4 m2 = Mr[q4 * 4 + 2];
            float4 m3 = Mr[q4 * 4 + 3];
            #pragma unroll
            for (int pi = 0; pi < 6; ++pi) {
                const float4* wq = (const float4*)&win[(pb6 + pi) * 68 + q4 * 16];
                float4 w0 = wq[0], w1 = wq[1], w2 = wq[2], w3 = wq[3];
                acc[pi] += w0.x * m0.x + w0.y * m0.y + w0.z * m0.z + w0.w * m0.w
                         + w1.x * m1.x + w1.y * m1.y + w1.z * m1.z + w1.w * m1.w
                         + w2.x * m2.x + w2.y * m2.y + w2.z * m2.z + w2.w * m2.w
                         + w3.x * m3.x + w3.y * m3.y + w3.z * m3.z + w3.w * m3.w;
            }
        }
        #pragma unroll
        for (int pi = 0; pi < 6; ++pi)
            xls[(pb6 + pi) * 68 + lane] = acc[pi];   // banks (4p+j)%32: 2-way
    }

    // ---- Seeds: d_k[jl] = c1v*cos(k*theta); c1v folded into seeds ----
    float A[8], ce[8], co[8];
    {
        float4 pr0 = *(const float4*)&P[lane * 64 + jb];
        float4 pr1 = *(const float4*)&P[lane * 64 + jb + 4];
        float pv[8] = {pr0.x, pr0.y, pr0.z, pr0.w, pr1.x, pr1.y, pr1.z, pr1.w};
        float k1f = (float)k1, k2f = (float)k2s;
        #pragma unroll
        for (int jl = 0; jl < 8; ++jl) {
            float T  = (float)(lane * 64 + jb + jl + 2);
            float rT = __builtin_amdgcn_rcpf(T);
            A[jl]    = 2.0f * cos_revr(1.0f, rT);
            float c1 = cos_revr(k1f, rT) * pv[jl];
            ce[jl]   = cos_revr(k2f, rT) * c1;          // d_{k2s}
            co[jl]   = cos_revr(k2f - 1.0f, rT) * c1;   // d_{k2s-1}
        }
    }
    __syncthreads();                    // sync2: xls visible; win dead -> part

    // base pointers: inner offsets become compile-time immediates
    float* pw = part + w * 1536 + lane;         // part[w][s][lane], +s*64
    const float* pr = part + t;                 // reduce base, +ww*1536
    float* outp = out + ((size_t)k1 * NW + k2s) * 64 + t;   // +sub*1536+e

    // ---- Phase D: 2 subs x 24 steps; xs = uniform LDS b128 broadcast ----
    #pragma unroll
    for (int sub = 0; sub < 2; ++sub) {
        #pragma unroll
        for (int m = 0; m < 12; ++m) {
            {   // even step: current = ce, advance co
                const int s = 2 * m;
                const int k2i = sub * 24 + s;   // compile-time
                const float4* xq = (const float4*)&xls[k2i * 68 + jb];  // uniform
                float4 q0 = xq[0], q1 = xq[1];
                float xs[8] = {q0.x, q0.y, q0.z, q0.w, q1.x, q1.y, q1.z, q1.w};
                float pa = 0.f, pb = 0.f;       // two 4-deep chains
                #pragma unroll
                for (int jl = 0; jl < 4; ++jl) {
                    pa     = fmaf(xs[jl], ce[jl], pa);
                    co[jl] = fmaf(A[jl], ce[jl], -co[jl]);
                }
                #pragma unroll
                for (int jl = 4; jl < 8; ++jl) {
                    pb     = fmaf(xs[jl], ce[jl], pb);
                    co[jl] = fmaf(A[jl], ce[jl], -co[jl]);
                }
                pw[s * 64] = pa + pb;           // ds_write, imm offset
            }
            {   // odd step: current = co, advance ce
                const int s = 2 * m + 1;
                const int k2i = sub * 24 + s;
                const float4* xq = (const float4*)&xls[k2i * 68 + jb];  // uniform
                float4 q0 = xq[0], q1 = xq[1];
                float xs[8] = {q0.x, q0.y, q0.z, q0.w, q1.x, q1.y, q1.z, q1.w};
                float pa = 0.f, pb = 0.f;
                #pragma unroll
                for (int jl = 0; jl < 4; ++jl) {
                    pa     = fmaf(xs[jl], co[jl], pa);
                    ce[jl] = fmaf(A[jl], co[jl], -ce[jl]);
                }
                #pragma unroll
                for (int jl = 4; jl < 8; ++jl) {
                    pb     = fmaf(xs[jl], co[jl], pb);
                    ce[jl] = fmaf(A[jl], co[jl], -ce[jl]);
                }
                pw[s * 64] = pa + pb;           // ds_write, imm offset
            }
        }
        __syncthreads();                // all 8x24 wave-partial slices written
        {   // reduce 8 wave-partials over 24 slots; 3 outputs/thread
            #pragma unroll
            for (int r = 0; r < 3; ++r) {
                const int e = r * 512;  // + t: k2l = (e+t)>>6, i = (e+t)&63
                float v = pr[e]           + pr[e + 1536]
                        + pr[e + 3072]    + pr[e + 4608]
                        + pr[e + 6144]    + pr[e + 7680]
                        + pr[e + 9216]    + pr[e + 10752];
                outp[sub * 1536 + e] = v;   // coalesced
            }
        }
        __syncthreads();                // part reusable next sub
    }
}

extern "C" void kernel_launch(void* const* d_in, const int* in_sizes, int n_in,
                              void* d_out, int out_size, void* d_ws, size_t ws_size,
                              hipStream_t stream) {
    const float* grid = (const float*)d_in[0];   // [193,193,64]
    const float* Mw   = (const float*)d_in[1];   // [64,64]
    const float* P    = (const float*)d_in[2];   // [64,64]
    float* out = (float*)d_out;                  // [36864,64]
    (void)d_ws; (void)ws_size;                   // workspace unused

    k_fused<<<NMAIN, 512, 0, stream>>>(grid, Mw, P, out);
}

// Round 17
// 85.343 us; speedup vs baseline: 1.0332x; 1.0332x over previous
//
#include <hip/hip_runtime.h>
#include <math.h>

#define NW 192
#define Wt 193
#define CHUNK 48           // k2 per block
#define NMAIN 768          // 192 k1 x 4 chunks; 512 thr -> exactly 3 blocks/CU

// cos(2*pi*num*rcpden) via HW cos (input in revolutions)
__device__ __forceinline__ float cos_revr(float num, float rcpden) {
    float rev = num * rcpden;
    rev = __builtin_amdgcn_fractf(rev);
    return __builtin_amdgcn_cosf(rev);
}

// ---------------- k_fused v17 == v11 (best measured: 85.85 us) ----------------
// Terminal revert. Block b: k1 = b>>2, chunk c = b&3 (k2 in [48c,48c+48)).
// 512 thr = 8 waves; wave w owns j in [8w, 8w+8).
// LDS: win 13KB + xls 13KB + part 16KB = 42.5KB -> 3 blocks/CU (24 waves).
// A: win[p][c] coalesced into LDS (lane = c).
// B: lane = p (<48): win rows per-lane LDS b128; M rows wave-uniform s_load;
//    x -> xls[p][j] (LDS).
// Seeds: d_k = (cos(k1 th)*P[i][j]) * cos(k th) folded into recurrence seeds;
//    P read per-lane from global (16 KB, L2-hot).
// D: Chebyshev steps; xs via wave-uniform LDS b128 broadcast; 16 fma/step;
//    part[8][8][64] cross-wave j-reduce, coalesced out stores.
__global__ __launch_bounds__(512, 4) void k_fused(const float* __restrict__ grid,
                                                  const float* __restrict__ Mw,
                                                  const float* __restrict__ P,
                                                  float* __restrict__ out) {
    __shared__ float win[CHUNK * 68];   // [p][c], stride 68
    __shared__ float xls[CHUNK * 68];   // [p][j], stride 68
    __shared__ float part[4096];        // [w 8][k2slot 8][i 64] = 16 KB

    int bx = blockIdx.x;
    int k1  = bx >> 2;                  // 0..191
    int k2s = (bx & 3) * CHUNK;         // 0,48,96,144
    int t = threadIdx.x;
    int lane = t & 63;
    int w = __builtin_amdgcn_readfirstlane(t >> 6);   // 0..7
    int jb = w * 8;

    // ---- Phase A: window averages, coalesced (lane = channel c) ----
    {
        int c = lane;
        const float* gb  = grid + ((size_t)k1 * Wt + k2s) * 64 + c;
        const float* gb1 = gb + (size_t)Wt * 64;
        #pragma unroll
        for (int r = 0; r < 6; ++r) {
            int p = w * 6 + r;          // 8 waves x 6 = 48 positions
            float s = gb[p * 64] + gb[(p + 1) * 64]
                    + gb1[p * 64] + gb1[(p + 1) * 64];
            win[p * 68 + c] = 0.25f * s;
        }
    }
    __syncthreads();                    // sync1: win visible

    // ---- Phase B: x[p][jb..jb+8) (lane = p; M via wave-uniform s_load) ----
    if (lane < CHUNK) {
        float accj[8];
        #pragma unroll
        for (int r = 0; r < 8; ++r) accj[r] = 0.f;
        #pragma unroll
        for (int q4 = 0; q4 < 4; ++q4) {
            float4 wv0 = *(const float4*)&win[lane * 68 + q4 * 16];
            float4 wv1 = *(const float4*)&win[lane * 68 + q4 * 16 + 4];
            float4 wv2 = *(const float4*)&win[lane * 68 + q4 * 16 + 8];
            float4 wv3 = *(const float4*)&win[lane * 68 + q4 * 16 + 12];
            #pragma unroll
            for (int r = 0; r < 8; ++r) {
                // wave-uniform address -> s_load_dwordx4 (scalar cache)
                const float4* mr = (const float4*)&Mw[(jb + r) * 64 + q4 * 16];
                float4 m0 = mr[0], m1 = mr[1], m2 = mr[2], m3 = mr[3];
                accj[r] += wv0.x * m0.x + wv0.y * m0.y + wv0.z * m0.z + wv0.w * m0.w
                         + wv1.x * m1.x + wv1.y * m1.y + wv1.z * m1.z + wv1.w * m1.w
                         + wv2.x * m2.x + wv2.y * m2.y + wv2.z * m2.z + wv2.w * m2.w
                         + wv3.x * m3.x + wv3.y * m3.y + wv3.z * m3.z + wv3.w * m3.w;
            }
        }
        #pragma unroll
        for (int r = 0; r < 8; ++r)
            xls[lane * 68 + jb + r] = accj[r];
    }

    // ---- Seeds (independent of xls; overlaps phase B tail) ----
    // d_k[jl] = c1v*cos(k*theta): same 2-term recurrence, c1v folded in.
    float A[8], ce[8], co[8];
    {
        float4 pr0 = *(const float4*)&P[lane * 64 + jb];
        float4 pr1 = *(const float4*)&P[lane * 64 + jb + 4];
        float pv[8] = {pr0.x, pr0.y, pr0.z, pr0.w, pr1.x, pr1.y, pr1.z, pr1.w};
        float k1f = (float)k1, k2f = (float)k2s;
        #pragma unroll
        for (int jl = 0; jl < 8; ++jl) {
            float T  = (float)(lane * 64 + jb + jl + 2);
            float rT = __builtin_amdgcn_rcpf(T);
            A[jl]    = 2.0f * cos_revr(1.0f, rT);
            float c1 = cos_revr(k1f, rT) * pv[jl];
            ce[jl]   = cos_revr(k2f, rT) * c1;          // d_{k2s}
            co[jl]   = cos_revr(k2f - 1.0f, rT) * c1;   // d_{k2s-1}
        }
    }
    __syncthreads();                    // sync2: xls visible

    // ---- Phase D: 6 subs x 8 k2 steps; xs = uniform LDS b128 broadcast ----
    #pragma unroll
    for (int sub = 0; sub < 6; ++sub) {
        #pragma unroll
        for (int m = 0; m < 4; ++m) {
            {   // even step: current = ce, advance co
                int s = 2 * m;
                int k2i = sub * 8 + s;
                const float4* xq = (const float4*)&xls[k2i * 68 + jb];  // uniform
                float4 q0 = xq[0], q1 = xq[1];
                float xs[8] = {q0.x, q0.y, q0.z, q0.w, q1.x, q1.y, q1.z, q1.w};
                float pa = 0.f, pb = 0.f;       // two 4-deep chains
                #pragma unroll
                for (int jl = 0; jl < 4; ++jl) {
                    pa     = fmaf(xs[jl], ce[jl], pa);
                    co[jl] = fmaf(A[jl], ce[jl], -co[jl]);
                }
                #pragma unroll
                for (int jl = 4; jl < 8; ++jl) {
                    pb     = fmaf(xs[jl], ce[jl], pb);
                    co[jl] = fmaf(A[jl], ce[jl], -co[jl]);
                }
                part[(w * 8 + s) * 64 + lane] = pa + pb;
            }
            {   // odd step: current = co, advance ce
                int s = 2 * m + 1;
                int k2i = sub * 8 + s;
                const float4* xq = (const float4*)&xls[k2i * 68 + jb];  // uniform
                float4 q0 = xq[0], q1 = xq[1];
                float xs[8] = {q0.x, q0.y, q0.z, q0.w, q1.x, q1.y, q1.z, q1.w};
                float pa = 0.f, pb = 0.f;
                #pragma unroll
                for (int jl = 0; jl < 4; ++jl) {
                    pa     = fmaf(xs[jl], co[jl], pa);
                    ce[jl] = fmaf(A[jl], co[jl], -ce[jl]);
                }
                #pragma unroll
                for (int jl = 4; jl < 8; ++jl) {
                    pb     = fmaf(xs[jl], co[jl], pb);
                    ce[jl] = fmaf(A[jl], co[jl], -ce[jl]);
                }
                part[(w * 8 + s) * 64 + lane] = pa + pb;
            }
        }
        __syncthreads();                // all 8 wave-partial slices written
        {   // reduce 8 wave-partials; 512 thr = one (k2slot,i) each; coalesced
            float r = part[t];
            #pragma unroll
            for (int ww = 1; ww < 8; ++ww) r += part[ww * 512 + t];
            out[((size_t)k1 * NW + (k2s + sub * 8 + (t >> 6))) * 64 + (t & 63)] = r;
        }
        __syncthreads();                // part reusable next sub
    }
}

extern "C" void kernel_launch(void* const* d_in, const int* in_sizes, int n_in,
                              void* d_out, int out_size, void* d_ws, size_t ws_size,
                              hipStream_t stream) {
    const float* grid = (const float*)d_in[0];   // [193,193,64]
    const float* Mw   = (const float*)d_in[1];   // [64,64]
    const float* P    = (const float*)d_in[2];   // [64,64]
    float* out = (float*)d_out;                  // [36864,64]
    (void)d_ws; (void)ws_size;                   // workspace unused

    k_fused<<<NMAIN, 512, 0, stream>>>(grid, Mw, P, out);
}

// Round 18
// 83.507 us; speedup vs baseline: 1.0560x; 1.0220x over previous
//
#include <hip/hip_runtime.h>
#include <math.h>

#define NW 192
#define Wt 193
#define CHUNK 48           // k2 per block
#define NMAIN 768          // 192 k1 x 4 chunks; 512 thr -> exactly 3 blocks/CU

typedef float v2f __attribute__((ext_vector_type(2)));

// cos(2*pi*num*rcpden) via HW cos (input in revolutions)
__device__ __forceinline__ float cos_revr(float num, float rcpden) {
    float rev = num * rcpden;
    rev = __builtin_amdgcn_fractf(rev);
    return __builtin_amdgcn_cosf(rev);
}

// ---------------- k_fused v18: v11 + packed-fp32 phase D ----------------
// Identical to v17 (best measured 85.3) except phase D runs on v_pk_fma_f32:
//  - xls write slots permuted: slot(r) = r<4 ? 2r : 2(r-4)+1, so a float4
//    read yields {x[u], x[u+4], x[u+1], x[u+5]} -> packed pairs (jl, jl+4)
//    land in adjacent VGPRs with zero shuffles.
//  - recurrence state A2/ce2/co2 stored as v2f pairs (jl, jl+4); the two
//    independent psum chains (pa/pb) become one packed chain ps.
//  - per step: 16 scalar FMA -> 8 pk-FMA issues (plus same LDS ops).
// Numerics: identical grouping (ps.x sums jl 0..3, ps.y sums jl 4..7).
__global__ __launch_bounds__(512, 4) void k_fused(const float* __restrict__ grid,
                                                  const float* __restrict__ Mw,
                                                  const float* __restrict__ P,
                                                  float* __restrict__ out) {
    __shared__ float win[CHUNK * 68];   // [p][c], stride 68
    __shared__ float xls[CHUNK * 68];   // [p][j-slot], stride 68 (permuted slots)
    __shared__ float part[4096];        // [w 8][k2slot 8][i 64] = 16 KB

    int bx = blockIdx.x;
    int k1  = bx >> 2;                  // 0..191
    int k2s = (bx & 3) * CHUNK;         // 0,48,96,144
    int t = threadIdx.x;
    int lane = t & 63;
    int w = __builtin_amdgcn_readfirstlane(t >> 6);   // 0..7
    int jb = w * 8;

    // ---- Phase A: window averages, coalesced (lane = channel c) ----
    {
        int c = lane;
        const float* gb  = grid + ((size_t)k1 * Wt + k2s) * 64 + c;
        const float* gb1 = gb + (size_t)Wt * 64;
        #pragma unroll
        for (int r = 0; r < 6; ++r) {
            int p = w * 6 + r;          // 8 waves x 6 = 48 positions
            float s = gb[p * 64] + gb[(p + 1) * 64]
                    + gb1[p * 64] + gb1[(p + 1) * 64];
            win[p * 68 + c] = 0.25f * s;
        }
    }
    __syncthreads();                    // sync1: win visible

    // ---- Phase B: x[p][jb..jb+8) (lane = p; M via wave-uniform s_load) ----
    if (lane < CHUNK) {
        float accj[8];
        #pragma unroll
        for (int r = 0; r < 8; ++r) accj[r] = 0.f;
        #pragma unroll
        for (int q4 = 0; q4 < 4; ++q4) {
            float4 wv0 = *(const float4*)&win[lane * 68 + q4 * 16];
            float4 wv1 = *(const float4*)&win[lane * 68 + q4 * 16 + 4];
            float4 wv2 = *(const float4*)&win[lane * 68 + q4 * 16 + 8];
            float4 wv3 = *(const float4*)&win[lane * 68 + q4 * 16 + 12];
            #pragma unroll
            for (int r = 0; r < 8; ++r) {
                // wave-uniform address -> s_load_dwordx4 (scalar cache)
                const float4* mr = (const float4*)&Mw[(jb + r) * 64 + q4 * 16];
                float4 m0 = mr[0], m1 = mr[1], m2 = mr[2], m3 = mr[3];
                accj[r] += wv0.x * m0.x + wv0.y * m0.y + wv0.z * m0.z + wv0.w * m0.w
                         + wv1.x * m1.x + wv1.y * m1.y + wv1.z * m1.z + wv1.w * m1.w
                         + wv2.x * m2.x + wv2.y * m2.y + wv2.z * m2.z + wv2.w * m2.w
                         + wv3.x * m3.x + wv3.y * m3.y + wv3.z * m3.z + wv3.w * m3.w;
            }
        }
        // permuted slots: r<4 -> 2r, r>=4 -> 2(r-4)+1  (pairs (u, u+4) adjacent)
        #pragma unroll
        for (int r = 0; r < 8; ++r) {
            int slot = (r < 4) ? (2 * r) : (2 * (r - 4) + 1);
            xls[lane * 68 + jb + slot] = accj[r];
        }
    }

    // ---- Seeds, packed: pair u = (jl=u, jl=u+4) ----
    // d_k = c1v*cos(k*theta): 2-term recurrence with c1v folded in.
    v2f A2[4], ce2[4], co2[4];
    {
        float4 pr0 = *(const float4*)&P[lane * 64 + jb];
        float4 pr1 = *(const float4*)&P[lane * 64 + jb + 4];
        float pv[8] = {pr0.x, pr0.y, pr0.z, pr0.w, pr1.x, pr1.y, pr1.z, pr1.w};
        float k1f = (float)k1, k2f = (float)k2s;
        #pragma unroll
        for (int u = 0; u < 4; ++u) {
            float T0 = (float)(lane * 64 + jb + u + 2);
            float T1 = T0 + 4.0f;
            float r0 = __builtin_amdgcn_rcpf(T0);
            float r1 = __builtin_amdgcn_rcpf(T1);
            A2[u] = (v2f){2.0f * cos_revr(1.0f, r0), 2.0f * cos_revr(1.0f, r1)};
            float c10 = cos_revr(k1f, r0) * pv[u];
            float c11 = cos_revr(k1f, r1) * pv[u + 4];
            ce2[u] = (v2f){cos_revr(k2f, r0) * c10,
                           cos_revr(k2f, r1) * c11};          // d_{k2s}
            co2[u] = (v2f){cos_revr(k2f - 1.0f, r0) * c10,
                           cos_revr(k2f - 1.0f, r1) * c11};   // d_{k2s-1}
        }
    }
    __syncthreads();                    // sync2: xls visible

    // ---- Phase D: 6 subs x 8 k2 steps; packed pk_fma pairs ----
    #pragma unroll
    for (int sub = 0; sub < 6; ++sub) {
        #pragma unroll
        for (int m = 0; m < 4; ++m) {
            {   // even step: current = ce2, advance co2
                int s = 2 * m;
                int k2i = sub * 8 + s;
                const float4* xq = (const float4*)&xls[k2i * 68 + jb];  // uniform
                float4 q0 = xq[0], q1 = xq[1];
                v2f x0 = {q0.x, q0.y};  // (x[jb+0], x[jb+4])
                v2f x1 = {q0.z, q0.w};  // (x[jb+1], x[jb+5])
                v2f x2 = {q1.x, q1.y};  // (x[jb+2], x[jb+6])
                v2f x3 = {q1.z, q1.w};  // (x[jb+3], x[jb+7])
                v2f ps = {0.f, 0.f};
                ps += x0 * ce2[0];  co2[0] = A2[0] * ce2[0] - co2[0];
                ps += x1 * ce2[1];  co2[1] = A2[1] * ce2[1] - co2[1];
                ps += x2 * ce2[2];  co2[2] = A2[2] * ce2[2] - co2[2];
                ps += x3 * ce2[3];  co2[3] = A2[3] * ce2[3] - co2[3];
                part[(w * 8 + s) * 64 + lane] = ps.x + ps.y;
            }
            {   // odd step: current = co2, advance ce2
                int s = 2 * m + 1;
                int k2i = sub * 8 + s;
                const float4* xq = (const float4*)&xls[k2i * 68 + jb];  // uniform
                float4 q0 = xq[0], q1 = xq[1];
                v2f x0 = {q0.x, q0.y};
                v2f x1 = {q0.z, q0.w};
                v2f x2 = {q1.x, q1.y};
                v2f x3 = {q1.z, q1.w};
                v2f ps = {0.f, 0.f};
                ps += x0 * co2[0];  ce2[0] = A2[0] * co2[0] - ce2[0];
                ps += x1 * co2[1];  ce2[1] = A2[1] * co2[1] - ce2[1];
                ps += x2 * co2[2];  ce2[2] = A2[2] * co2[2] - ce2[2];
                ps += x3 * co2[3];  ce2[3] = A2[3] * co2[3] - ce2[3];
                part[(w * 8 + s) * 64 + lane] = ps.x + ps.y;
            }
        }
        __syncthreads();                // all 8 wave-partial slices written
        {   // reduce 8 wave-partials; 512 thr = one (k2slot,i) each; coalesced
            float r = part[t];
            #pragma unroll
            for (int ww = 1; ww < 8; ++ww) r += part[ww * 512 + t];
            out[((size_t)k1 * NW + (k2s + sub * 8 + (t >> 6))) * 64 + (t & 63)] = r;
        }
        __syncthreads();                // part reusable next sub
    }
}

extern "C" void kernel_launch(void* const* d_in, const int* in_sizes, int n_in,
                              void* d_out, int out_size, void* d_ws, size_t ws_size,
                              hipStream_t stream) {
    const float* grid = (const float*)d_in[0];   // [193,193,64]
    const float* Mw   = (const float*)d_in[1];   // [64,64]
    const float* P    = (const float*)d_in[2];   // [64,64]
    float* out = (float*)d_out;                  // [36864,64]
    (void)d_ws; (void)ws_size;                   // workspace unused

    k_fused<<<NMAIN, 512, 0, stream>>>(grid, Mw, P, out);
}

// Round 19
// 81.728 us; speedup vs baseline: 1.0789x; 1.0218x over previous
//
#include <hip/hip_runtime.h>
#include <math.h>

#define NW 192
#define Wt 193
#define CHUNK 48           // k2 per block
#define NMAIN 768          // 192 k1 x 4 chunks; 512 thr -> exactly 3 blocks/CU

typedef float v2f __attribute__((ext_vector_type(2)));

// cos(2*pi*num*rcpden) via HW cos (input in revolutions)
__device__ __forceinline__ float cos_revr(float num, float rcpden) {
    float rev = num * rcpden;
    rev = __builtin_amdgcn_fractf(rev);
    return __builtin_amdgcn_cosf(rev);
}

// ---------------- k_fused v19: v18 + packed phase B ----------------
// v18 (83.5 us, best) + issue cuts in the remaining scalar-FMA block:
//  - Phase B packed: acc2[r] (v2f) += {wv.x,wv.y}*{m.x,m.y} pairs over c.
//    512 scalar FMA -> 256 pk_fma (+8 final adds). M pairs are adjacent
//    SGPRs from s_load_dwordx4 (pk-FMA allows one SGPR-pair operand);
//    wv pairs are adjacent VGPRs from ds_read_b128.
//  - Phase D: ps zero-init folded into leading pk-mul (-1 issue/step).
//  - part writes/reads via base pointer + compile-time immediate offsets.
// Everything else byte-identical to v18.
__global__ __launch_bounds__(512, 4) void k_fused(const float* __restrict__ grid,
                                                  const float* __restrict__ Mw,
                                                  const float* __restrict__ P,
                                                  float* __restrict__ out) {
    __shared__ float win[CHUNK * 68];   // [p][c], stride 68
    __shared__ float xls[CHUNK * 68];   // [p][j-slot], stride 68 (permuted slots)
    __shared__ float part[4096];        // [w 8][k2slot 8][i 64] = 16 KB

    int bx = blockIdx.x;
    int k1  = bx >> 2;                  // 0..191
    int k2s = (bx & 3) * CHUNK;         // 0,48,96,144
    int t = threadIdx.x;
    int lane = t & 63;
    int w = __builtin_amdgcn_readfirstlane(t >> 6);   // 0..7
    int jb = w * 8;

    // ---- Phase A: window averages, coalesced (lane = channel c) ----
    {
        int c = lane;
        const float* gb  = grid + ((size_t)k1 * Wt + k2s) * 64 + c;
        const float* gb1 = gb + (size_t)Wt * 64;
        #pragma unroll
        for (int r = 0; r < 6; ++r) {
            int p = w * 6 + r;          // 8 waves x 6 = 48 positions
            float s = gb[p * 64] + gb[(p + 1) * 64]
                    + gb1[p * 64] + gb1[(p + 1) * 64];
            win[p * 68 + c] = 0.25f * s;
        }
    }
    __syncthreads();                    // sync1: win visible

    // ---- Phase B (packed): x[p][jb..jb+8) (lane = p; M via s_load) ----
    if (lane < CHUNK) {
        v2f acc2[8];
        #pragma unroll
        for (int r = 0; r < 8; ++r) acc2[r] = (v2f){0.f, 0.f};
        #pragma unroll
        for (int q4 = 0; q4 < 4; ++q4) {
            float4 wv0 = *(const float4*)&win[lane * 68 + q4 * 16];
            float4 wv1 = *(const float4*)&win[lane * 68 + q4 * 16 + 4];
            float4 wv2 = *(const float4*)&win[lane * 68 + q4 * 16 + 8];
            float4 wv3 = *(const float4*)&win[lane * 68 + q4 * 16 + 12];
            v2f wa = {wv0.x, wv0.y}, wb = {wv0.z, wv0.w};
            v2f wc = {wv1.x, wv1.y}, wd = {wv1.z, wv1.w};
            v2f we = {wv2.x, wv2.y}, wf = {wv2.z, wv2.w};
            v2f wg = {wv3.x, wv3.y}, wh = {wv3.z, wv3.w};
            #pragma unroll
            for (int r = 0; r < 8; ++r) {
                // wave-uniform address -> s_load_dwordx4 (scalar cache)
                const float4* mr = (const float4*)&Mw[(jb + r) * 64 + q4 * 16];
                float4 m0 = mr[0], m1 = mr[1], m2 = mr[2], m3 = mr[3];
                acc2[r] += wa * (v2f){m0.x, m0.y};
                acc2[r] += wb * (v2f){m0.z, m0.w};
                acc2[r] += wc * (v2f){m1.x, m1.y};
                acc2[r] += wd * (v2f){m1.z, m1.w};
                acc2[r] += we * (v2f){m2.x, m2.y};
                acc2[r] += wf * (v2f){m2.z, m2.w};
                acc2[r] += wg * (v2f){m3.x, m3.y};
                acc2[r] += wh * (v2f){m3.z, m3.w};
            }
        }
        // permuted slots: r<4 -> 2r, r>=4 -> 2(r-4)+1  (pairs (u, u+4) adjacent)
        #pragma unroll
        for (int r = 0; r < 8; ++r) {
            int slot = (r < 4) ? (2 * r) : (2 * (r - 4) + 1);
            xls[lane * 68 + jb + slot] = acc2[r].x + acc2[r].y;
        }
    }

    // ---- Seeds, packed: pair u = (jl=u, jl=u+4) ----
    // d_k = c1v*cos(k*theta): 2-term recurrence with c1v folded in.
    v2f A2[4], ce2[4], co2[4];
    {
        float4 pr0 = *(const float4*)&P[lane * 64 + jb];
        float4 pr1 = *(const float4*)&P[lane * 64 + jb + 4];
        float pv[8] = {pr0.x, pr0.y, pr0.z, pr0.w, pr1.x, pr1.y, pr1.z, pr1.w};
        float k1f = (float)k1, k2f = (float)k2s;
        #pragma unroll
        for (int u = 0; u < 4; ++u) {
            float T0 = (float)(lane * 64 + jb + u + 2);
            float T1 = T0 + 4.0f;
            float r0 = __builtin_amdgcn_rcpf(T0);
            float r1 = __builtin_amdgcn_rcpf(T1);
            A2[u] = (v2f){2.0f * cos_revr(1.0f, r0), 2.0f * cos_revr(1.0f, r1)};
            float c10 = cos_revr(k1f, r0) * pv[u];
            float c11 = cos_revr(k1f, r1) * pv[u + 4];
            ce2[u] = (v2f){cos_revr(k2f, r0) * c10,
                           cos_revr(k2f, r1) * c11};          // d_{k2s}
            co2[u] = (v2f){cos_revr(k2f - 1.0f, r0) * c10,
                           cos_revr(k2f - 1.0f, r1) * c11};   // d_{k2s-1}
        }
    }
    __syncthreads();                    // sync2: xls visible

    // base pointers: inner offsets become compile-time immediates
    float* pw = part + w * 512 + lane;          // part[w][s][lane], +s*64
    const float* pr = part + t;                 // reduce base, +ww*512
    float* outp = out + ((size_t)k1 * NW + k2s) * 64 + t;   // +sub*512

    // ---- Phase D: 6 subs x 8 k2 steps; packed pk_fma pairs ----
    #pragma unroll
    for (int sub = 0; sub < 6; ++sub) {
        #pragma unroll
        for (int m = 0; m < 4; ++m) {
            {   // even step: current = ce2, advance co2
                const int s = 2 * m;
                const int k2i = sub * 8 + s;
                const float4* xq = (const float4*)&xls[k2i * 68 + jb];  // uniform
                float4 q0 = xq[0], q1 = xq[1];
                v2f x0 = {q0.x, q0.y};  // (x[jb+0], x[jb+4])
                v2f x1 = {q0.z, q0.w};  // (x[jb+1], x[jb+5])
                v2f x2 = {q1.x, q1.y};  // (x[jb+2], x[jb+6])
                v2f x3 = {q1.z, q1.w};  // (x[jb+3], x[jb+7])
                v2f ps = x0 * ce2[0];   co2[0] = A2[0] * ce2[0] - co2[0];
                ps += x1 * ce2[1];      co2[1] = A2[1] * ce2[1] - co2[1];
                ps += x2 * ce2[2];      co2[2] = A2[2] * ce2[2] - co2[2];
                ps += x3 * ce2[3];      co2[3] = A2[3] * ce2[3] - co2[3];
                pw[s * 64] = ps.x + ps.y;       // ds_write, imm offset
            }
            {   // odd step: current = co2, advance ce2
                const int s = 2 * m + 1;
                const int k2i = sub * 8 + s;
                const float4* xq = (const float4*)&xls[k2i * 68 + jb];  // uniform
                float4 q0 = xq[0], q1 = xq[1];
                v2f x0 = {q0.x, q0.y};
                v2f x1 = {q0.z, q0.w};
                v2f x2 = {q1.x, q1.y};
                v2f x3 = {q1.z, q1.w};
                v2f ps = x0 * co2[0];   ce2[0] = A2[0] * co2[0] - ce2[0];
                ps += x1 * co2[1];      ce2[1] = A2[1] * co2[1] - ce2[1];
                ps += x2 * co2[2];      ce2[2] = A2[2] * co2[2] - ce2[2];
                ps += x3 * co2[3];      ce2[3] = A2[3] * co2[3] - ce2[3];
                pw[s * 64] = ps.x + ps.y;       // ds_write, imm offset
            }
        }
        __syncthreads();                // all 8 wave-partial slices written
        {   // reduce 8 wave-partials; imm-offset reads; coalesced store
            float r = pr[0]    + pr[512]  + pr[1024] + pr[1536]
                    + pr[2048] + pr[2560] + pr[3072] + pr[3584];
            outp[sub * 512] = r;
        }
        __syncthreads();                // part reusable next sub
    }
}

extern "C" void kernel_launch(void* const* d_in, const int* in_sizes, int n_in,
                              void* d_out, int out_size, void* d_ws, size_t ws_size,
                              hipStream_t stream) {
    const float* grid = (const float*)d_in[0];   // [193,193,64]
    const float* Mw   = (const float*)d_in[1];   // [64,64]
    const float* P    = (const float*)d_in[2];   // [64,64]
    float* out = (float*)d_out;                  // [36864,64]
    (void)d_ws; (void)ws_size;                   // workspace unused

    k_fused<<<NMAIN, 512, 0, stream>>>(grid, Mw, P, out);
}